// Round 12
// baseline (91.989 us; speedup 1.0000x reference)
//
#include <hip/hip_runtime.h>
#include <hip/hip_bf16.h>
#include <math.h>

// SLAYFeatures via MFMA: out[b, h*64 + n] = f(proj, r), n = r*32+m,
// proj = x_norm . omega[r,h,:,m].  x[B,H*D] fp32, omega[R,H,D,M] fp32.
// B=65536,H=16,D=64,M=32,R=2. N=R*M=64.
//
// Round-12 change: TWO heads per block (head-pair). Rationale: three TLP
// null-results pin effective DRAM BW at ~4.4 TB/s; both streams touch 256B
// chunks at 4KB stride (x reads: h-slice; out writes: h-slice). Doubling
// the per-row contiguous run to 512B (adjacent heads) is the chunk-size
// lever. Same 6-MFMA hi/lo pipeline per head; omega planes for both heads
// in LDS (32KB); out bounce 512B/row per wave (32KB).

#define HH 16
#define DD 64
#define MM 32
#define RR 2
#define NN (RR*MM)          // 64 output cols per head
#define TILE_B 512
#define NST (TILE_B/64)     // 8 sub-tiles

using short8  = __attribute__((ext_vector_type(8))) short;
using floatx4 = __attribute__((ext_vector_type(4))) float;

__device__ __forceinline__ short bf16_hi(float v) {
    __hip_bfloat16 b = __float2bfloat16(v);      // RNE; pairs fuse to v_cvt_pk_bf16_f32
    return __builtin_bit_cast(short, b);
}
__device__ __forceinline__ float bf16_f(short s) {
    return __uint_as_float(((unsigned)(unsigned short)s) << 16);
}

__global__ __launch_bounds__(256, 2)
void slay_mfma_kernel(const float* __restrict__ x,
                      const float* __restrict__ omega,
                      const float* __restrict__ qn,
                      const float* __restrict__ qw,
                      float* __restrict__ out)
{
    __shared__ short lds_hi[2][NN * DD];     // per-head hi plane, swizzled (16KB)
    __shared__ short lds_lo[2][NN * DD];     // per-head lo plane (16KB)
    __shared__ float lds_oc[4][16 * 128];    // per-wave bounce [16 rows][512B] (32KB)

    const int tid  = threadIdx.x;
    const int lane = tid & 63;
    const int wv   = tid >> 6;
    const int hp   = blockIdx.x & (HH / 2 - 1);   // head pair 0..7
    const int tile = blockIdx.x >> 3;
    const int h0   = hp * 2;

    const int mrow = lane & 15;    // b-row index within wave tile
    const int g    = lane >> 4;    // k-group 0..3

    // ---- stage omega for heads h0,h0+1 -> bf16 hi/lo planes [n=r*32+m][k=d] ----
    #pragma unroll
    for (int i = 0; i < (2 * RR * DD * MM) / 256; ++i) {
        int e  = i * 256 + tid;
        int hh = e >> 12;              // head-within-pair
        int rr = (e >> 11) & 1;
        int d  = (e >> 5) & (DD - 1);
        int m  = e & (MM - 1);
        float v = omega[((size_t)(rr * HH + h0 + hh) * DD + d) * MM + m];
        short hi = bf16_hi(v);
        short lo = bf16_hi(v - bf16_f(hi));
        int n   = rr * MM + m;
        int byt = (d * 2) ^ ((n & 7) << 4);           // XOR swizzle within 128B row
        *(short*)((char*)lds_hi[hh] + n * (DD * 2) + byt) = hi;
        *(short*)((char*)lds_lo[hh] + n * (DD * 2) + byt) = lo;
    }
    __syncthreads();

    // quadrature scalars (uniform)
    const float sn[2]  = { qn[0], qn[1] };
    const float s2s[2] = { sqrtf(2.f * fmaxf(sn[0], 0.f)), sqrtf(2.f * fmaxf(sn[1], 0.f)) };
    const float cr[2]  = { sqrtf(fmaxf(qw[0], 0.f)) * (1.f / MM),
                           sqrtf(fmaxf(qw[1], 0.f)) * (1.f / MM) };

    const int sw = (mrow & 7) << 4;   // swizzle key (LDS row n = nt*16+mrow)
    char* const wb = (char*)lds_oc[wv];

    const float* xr0 = x + (size_t)(tile * TILE_B + wv * 16 + mrow) * (HH * DD) + h0 * DD;

    #pragma unroll
    for (int st = 0; st < NST; ++st) {
        const float* xr = xr0 + (size_t)st * 64 * (HH * DD);
        const int b_base = tile * TILE_B + st * 64 + wv * 16;

        // ---- load 32 x values: both heads' slices (512B/row contiguous run) ----
        float xv[32];
        *(float4*)(xv + 0)  = *(const float4*)(xr + g * 8);
        *(float4*)(xv + 4)  = *(const float4*)(xr + g * 8 + 4);
        *(float4*)(xv + 8)  = *(const float4*)(xr + 32 + g * 8);
        *(float4*)(xv + 12) = *(const float4*)(xr + 32 + g * 8 + 4);
        *(float4*)(xv + 16) = *(const float4*)(xr + 64 + g * 8);
        *(float4*)(xv + 20) = *(const float4*)(xr + 64 + g * 8 + 4);
        *(float4*)(xv + 24) = *(const float4*)(xr + 96 + g * 8);
        *(float4*)(xv + 28) = *(const float4*)(xr + 96 + g * 8 + 4);

        // ---- fp32 row norms, one per head ----
        float rnorm[2];
        #pragma unroll
        for (int hh = 0; hh < 2; ++hh) {
            float ss = 0.f;
            #pragma unroll
            for (int j = 0; j < 16; ++j) ss = fmaf(xv[hh * 16 + j], xv[hh * 16 + j], ss);
            ss += __shfl_xor(ss, 16, 64);
            ss += __shfl_xor(ss, 32, 64);
            rnorm[hh] = 1.0f / fmaxf(sqrtf(ss), 1e-6f);
        }

        #pragma unroll
        for (int hh = 0; hh < 2; ++hh) {
            // ---- bf16 hi/lo x fragments for this head ----
            short8 x_hi[2], x_lo[2];
            #pragma unroll
            for (int kc = 0; kc < 2; ++kc)
                #pragma unroll
                for (int j = 0; j < 8; ++j) {
                    float v  = xv[hh * 16 + kc * 8 + j];
                    short hi = bf16_hi(v);
                    x_hi[kc][j] = hi;
                    x_lo[kc][j] = bf16_hi(v - bf16_f(hi));
                }

            #pragma unroll
            for (int nt = 0; nt < 4; ++nt) {
                const char* rh = (const char*)lds_hi[hh] + (nt * 16 + mrow) * (DD * 2);
                const char* rl = (const char*)lds_lo[hh] + (nt * 16 + mrow) * (DD * 2);
                const int k0 = (g * 16) ^ sw;
                const int k1 = (64 + g * 16) ^ sw;
                short8 oh0 = *(const short8*)(rh + k0);
                short8 oh1 = *(const short8*)(rh + k1);
                short8 ol0 = *(const short8*)(rl + k0);
                short8 ol1 = *(const short8*)(rl + k1);

                floatx4 acc = {0.f, 0.f, 0.f, 0.f};
                acc = __builtin_amdgcn_mfma_f32_16x16x32_bf16(oh0, x_hi[0], acc, 0, 0, 0);
                acc = __builtin_amdgcn_mfma_f32_16x16x32_bf16(oh1, x_hi[1], acc, 0, 0, 0);
                acc = __builtin_amdgcn_mfma_f32_16x16x32_bf16(oh0, x_lo[0], acc, 0, 0, 0);
                acc = __builtin_amdgcn_mfma_f32_16x16x32_bf16(oh1, x_lo[1], acc, 0, 0, 0);
                acc = __builtin_amdgcn_mfma_f32_16x16x32_bf16(ol0, x_hi[0], acc, 0, 0, 0);
                acc = __builtin_amdgcn_mfma_f32_16x16x32_bf16(ol1, x_hi[1], acc, 0, 0, 0);

                const int r = nt >> 1;
                floatx4 res;
                #pragma unroll
                for (int q = 0; q < 4; ++q) {
                    float proj = acc[q] * rnorm[hh];
                    float ea = fmaf(proj, s2s[r], -sn[r]);
                    ea = fminf(fmaxf(ea, -10.f), 10.f);
                    res[q] = proj * proj * __expf(ea) * cr[r];
                }
                // bounce: row mrow, logical byte col = hh*256 + nt*64 + g*16
                *(floatx4*)(wb + mrow * 512 + ((hh * 256 + nt * 64 + g * 16) ^ sw)) = res;
            }
        }

        // ---- transposed read-back + contiguous stores (2 rows x 512B per instr) ----
        #pragma unroll
        for (int i = 0; i < 8; ++i) {
            const int row  = i * 2 + (lane >> 5);     // 0..15
            const int colb = (lane & 31) * 16;        // byte col within 512B
            floatx4 v = *(const floatx4*)(wb + row * 512 + (colb ^ ((row & 7) << 4)));
            float* op = out + (size_t)(b_base + row) * (HH * NN) + h0 * NN + (lane & 31) * 4;
            __builtin_nontemporal_store(v, (floatx4*)op);
        }
    }
}

extern "C" void kernel_launch(void* const* d_in, const int* in_sizes, int n_in,
                              void* d_out, int out_size, void* d_ws, size_t ws_size,
                              hipStream_t stream) {
    const float* x     = (const float*)d_in[0];
    const float* omega = (const float*)d_in[1];
    const float* qn    = (const float*)d_in[2];
    const float* qw    = (const float*)d_in[3];
    float* out = (float*)d_out;

    const int B = in_sizes[0] / (HH * DD);       // 65536
    dim3 grid((B / TILE_B) * (HH / 2));          // 128 tiles x 8 head-pairs = 1024
    dim3 block(256);

    slay_mfma_kernel<<<grid, block, 0, stream>>>(x, omega, qn, qw, out);
}

// Round 13
// 88.547 us; speedup vs baseline: 1.0389x; 1.0389x over previous
//
#include <hip/hip_runtime.h>
#include <hip/hip_bf16.h>
#include <math.h>

// SLAYFeatures via MFMA: out[b, h*64 + n] = f(proj, r), n = r*32+m,
// proj = x_norm . omega[r,h,:,m].  x[B,H*D] fp32, omega[R,H,D,M] fp32.
// B=65536,H=16,D=64,M=32,R=2. N=R*M=64.
//
// Two heads per block; omega in LDS as bf16 hi/lo planes (XOR-swizzled);
// 6x mfma_f32_16x16x32_bf16 hi/lo split; per-wave LDS out-bounce so stores
// are 2 rows x 512B contiguous per instr (WRITE_SIZE ideal 262MB).
//
// Round-13 change: XCD-GROUPING block swizzle. Previously bid = tile*8+hp
// round-robined the 8 same-tile blocks across 8 XCDs -> each XCD L2 held
// scattered 512B fragments of every 4KB out row; nt stores streamed them
// to DRAM unmerged (effective BW pinned ~4.4 TB/s across all TLP/chunk
// experiments). Remap so all 8 head-pair blocks of a tile share bid%8
// (same XCD): their writes merge in one L2 -> full-row DRAM bursts.
//   x8=bid&7; j=bid>>3; hp=j&7; tile=(j>>3)*8+x8   (bijective, 1024 blocks)

#define HH 16
#define DD 64
#define MM 32
#define RR 2
#define NN (RR*MM)          // 64 output cols per head
#define TILE_B 512
#define NST (TILE_B/64)     // 8 sub-tiles

using short8  = __attribute__((ext_vector_type(8))) short;
using floatx4 = __attribute__((ext_vector_type(4))) float;

__device__ __forceinline__ short bf16_hi(float v) {
    __hip_bfloat16 b = __float2bfloat16(v);      // RNE; pairs fuse to v_cvt_pk_bf16_f32
    return __builtin_bit_cast(short, b);
}
__device__ __forceinline__ float bf16_f(short s) {
    return __uint_as_float(((unsigned)(unsigned short)s) << 16);
}

__global__ __launch_bounds__(256, 2)
void slay_mfma_kernel(const float* __restrict__ x,
                      const float* __restrict__ omega,
                      const float* __restrict__ qn,
                      const float* __restrict__ qw,
                      float* __restrict__ out)
{
    __shared__ short lds_hi[2][NN * DD];     // per-head hi plane, swizzled (16KB)
    __shared__ short lds_lo[2][NN * DD];     // per-head lo plane (16KB)
    __shared__ float lds_oc[4][16 * 128];    // per-wave bounce [16 rows][512B] (32KB)

    const int tid  = threadIdx.x;
    const int lane = tid & 63;
    const int wv   = tid >> 6;

    // XCD-grouping remap: same-tile blocks share bid%8 -> same XCD L2
    const int bid  = blockIdx.x;
    const int x8   = bid & 7;
    const int j    = bid >> 3;
    const int hp   = j & 7;                       // head pair 0..7
    const int tile = ((j >> 3) << 3) | x8;        // 0..127
    const int h0   = hp * 2;

    const int mrow = lane & 15;    // b-row index within wave tile
    const int g    = lane >> 4;    // k-group 0..3

    // ---- stage omega for heads h0,h0+1 -> bf16 hi/lo planes [n=r*32+m][k=d] ----
    #pragma unroll
    for (int i = 0; i < (2 * RR * DD * MM) / 256; ++i) {
        int e  = i * 256 + tid;
        int hh = e >> 12;              // head-within-pair
        int rr = (e >> 11) & 1;
        int d  = (e >> 5) & (DD - 1);
        int m  = e & (MM - 1);
        float v = omega[((size_t)(rr * HH + h0 + hh) * DD + d) * MM + m];
        short hi = bf16_hi(v);
        short lo = bf16_hi(v - bf16_f(hi));
        int n   = rr * MM + m;
        int byt = (d * 2) ^ ((n & 7) << 4);           // XOR swizzle within 128B row
        *(short*)((char*)lds_hi[hh] + n * (DD * 2) + byt) = hi;
        *(short*)((char*)lds_lo[hh] + n * (DD * 2) + byt) = lo;
    }
    __syncthreads();

    // quadrature scalars (uniform)
    const float sn[2]  = { qn[0], qn[1] };
    const float s2s[2] = { sqrtf(2.f * fmaxf(sn[0], 0.f)), sqrtf(2.f * fmaxf(sn[1], 0.f)) };
    const float cr[2]  = { sqrtf(fmaxf(qw[0], 0.f)) * (1.f / MM),
                           sqrtf(fmaxf(qw[1], 0.f)) * (1.f / MM) };

    const int sw = (mrow & 7) << 4;   // swizzle key (LDS row n = nt*16+mrow)
    char* const wb = (char*)lds_oc[wv];

    const float* xr0 = x + (size_t)(tile * TILE_B + wv * 16 + mrow) * (HH * DD) + h0 * DD;

    #pragma unroll
    for (int st = 0; st < NST; ++st) {
        const float* xr = xr0 + (size_t)st * 64 * (HH * DD);
        const int b_base = tile * TILE_B + st * 64 + wv * 16;

        // ---- load 32 x values: both heads' slices (512B/row contiguous run) ----
        float xv[32];
        *(float4*)(xv + 0)  = *(const float4*)(xr + g * 8);
        *(float4*)(xv + 4)  = *(const float4*)(xr + g * 8 + 4);
        *(float4*)(xv + 8)  = *(const float4*)(xr + 32 + g * 8);
        *(float4*)(xv + 12) = *(const float4*)(xr + 32 + g * 8 + 4);
        *(float4*)(xv + 16) = *(const float4*)(xr + 64 + g * 8);
        *(float4*)(xv + 20) = *(const float4*)(xr + 64 + g * 8 + 4);
        *(float4*)(xv + 24) = *(const float4*)(xr + 96 + g * 8);
        *(float4*)(xv + 28) = *(const float4*)(xr + 96 + g * 8 + 4);

        // ---- fp32 row norms, one per head ----
        float rnorm[2];
        #pragma unroll
        for (int hh = 0; hh < 2; ++hh) {
            float ss = 0.f;
            #pragma unroll
            for (int j2 = 0; j2 < 16; ++j2) ss = fmaf(xv[hh * 16 + j2], xv[hh * 16 + j2], ss);
            ss += __shfl_xor(ss, 16, 64);
            ss += __shfl_xor(ss, 32, 64);
            rnorm[hh] = 1.0f / fmaxf(sqrtf(ss), 1e-6f);
        }

        #pragma unroll
        for (int hh = 0; hh < 2; ++hh) {
            // ---- bf16 hi/lo x fragments for this head ----
            short8 x_hi[2], x_lo[2];
            #pragma unroll
            for (int kc = 0; kc < 2; ++kc)
                #pragma unroll
                for (int j2 = 0; j2 < 8; ++j2) {
                    float v  = xv[hh * 16 + kc * 8 + j2];
                    short hi = bf16_hi(v);
                    x_hi[kc][j2] = hi;
                    x_lo[kc][j2] = bf16_hi(v - bf16_f(hi));
                }

            #pragma unroll
            for (int nt = 0; nt < 4; ++nt) {
                const char* rh = (const char*)lds_hi[hh] + (nt * 16 + mrow) * (DD * 2);
                const char* rl = (const char*)lds_lo[hh] + (nt * 16 + mrow) * (DD * 2);
                const int k0 = (g * 16) ^ sw;
                const int k1 = (64 + g * 16) ^ sw;
                short8 oh0 = *(const short8*)(rh + k0);
                short8 oh1 = *(const short8*)(rh + k1);
                short8 ol0 = *(const short8*)(rl + k0);
                short8 ol1 = *(const short8*)(rl + k1);

                floatx4 acc = {0.f, 0.f, 0.f, 0.f};
                acc = __builtin_amdgcn_mfma_f32_16x16x32_bf16(oh0, x_hi[0], acc, 0, 0, 0);
                acc = __builtin_amdgcn_mfma_f32_16x16x32_bf16(oh1, x_hi[1], acc, 0, 0, 0);
                acc = __builtin_amdgcn_mfma_f32_16x16x32_bf16(oh0, x_lo[0], acc, 0, 0, 0);
                acc = __builtin_amdgcn_mfma_f32_16x16x32_bf16(oh1, x_lo[1], acc, 0, 0, 0);
                acc = __builtin_amdgcn_mfma_f32_16x16x32_bf16(ol0, x_hi[0], acc, 0, 0, 0);
                acc = __builtin_amdgcn_mfma_f32_16x16x32_bf16(ol1, x_hi[1], acc, 0, 0, 0);

                const int r = nt >> 1;
                floatx4 res;
                #pragma unroll
                for (int q = 0; q < 4; ++q) {
                    float proj = acc[q] * rnorm[hh];
                    float ea = fmaf(proj, s2s[r], -sn[r]);
                    ea = fminf(fmaxf(ea, -10.f), 10.f);
                    res[q] = proj * proj * __expf(ea) * cr[r];
                }
                // bounce: row mrow, logical byte col = hh*256 + nt*64 + g*16
                *(floatx4*)(wb + mrow * 512 + ((hh * 256 + nt * 64 + g * 16) ^ sw)) = res;
            }
        }

        // ---- transposed read-back + contiguous stores (2 rows x 512B per instr) ----
        #pragma unroll
        for (int i = 0; i < 8; ++i) {
            const int row  = i * 2 + (lane >> 5);     // 0..15
            const int colb = (lane & 31) * 16;        // byte col within 512B
            floatx4 v = *(const floatx4*)(wb + row * 512 + (colb ^ ((row & 7) << 4)));
            float* op = out + (size_t)(b_base + row) * (HH * NN) + h0 * NN + (lane & 31) * 4;
            __builtin_nontemporal_store(v, (floatx4*)op);
        }
    }
}

extern "C" void kernel_launch(void* const* d_in, const int* in_sizes, int n_in,
                              void* d_out, int out_size, void* d_ws, size_t ws_size,
                              hipStream_t stream) {
    const float* x     = (const float*)d_in[0];
    const float* omega = (const float*)d_in[1];
    const float* qn    = (const float*)d_in[2];
    const float* qw    = (const float*)d_in[3];
    float* out = (float*)d_out;

    const int B = in_sizes[0] / (HH * DD);       // 65536
    dim3 grid((B / TILE_B) * (HH / 2));          // 128 tiles x 8 head-pairs = 1024
    dim3 block(256);

    slay_mfma_kernel<<<grid, block, 0, stream>>>(x, omega, qn, qw, out);
}